// Round 4
// baseline (131.455 us; speedup 1.0000x reference)
//
#include <hip/hip_runtime.h>

// GCN classifier, algebraically folded:
//   out = P (x @ (W1 @ W2)) + (bias[0]*sum(W2) + b2[0]),  P = D^-1/2 (A+I) D^-1/2
// NUM_CLASSES==1 collapses the MLP to one 48-vector dot per node (z = x.w);
// linearity lets us propagate scalars. Edge aggregation uses destination
// bucketing (512 ids/bucket) so degree & weighted-sum are LDS atomics, not
// global atomics (R1: 3.2M global atomics cost ~180us).
// R4: stagger cursor reservations by blockIdx (R3 had all blocks hitting
// cursor[t] in lock-step -> same-address atomic convoy); shuffle-based prep.

constexpr int kNodes  = 100000;
constexpr int kEdges  = 1600000;
constexpr int kFeat   = 48;
constexpr int kHidden = 256;

constexpr int kBShift = 9;                               // 512 node ids / bucket
constexpr int kBSize  = 1 << kBShift;
constexpr int kNB     = (kNodes + kBSize - 1) / kBSize;  // 196 buckets
constexpr int kCap    = 10240;   // slots/bucket; mean 8192, sigma~90 -> +22 sd
constexpr int kEPB    = 8192;    // edges per bucketing block (32/thread)
constexpr int kQuads  = kEdges / 4;                      // 400000 (exact)
constexpr int kBBlk   = (kEdges + kEPB - 1) / kEPB;      // 196 bucket blocks
constexpr int kZBlk   = (kNodes + 255) / 256;            // 391 z blocks

// prep: w[t] = sum_j W1[t][j]*W2[j]; c = bias[0]*sum(W2)+b2[0]; clear cursor.
// Shuffle-based: coalesced W1 reads, one __syncthreads, 768B LDS.
__global__ __launch_bounds__(256) void prep_kernel(const float* __restrict__ W1,
                                                   const float* __restrict__ bias,
                                                   const float* __restrict__ W2,
                                                   const float* __restrict__ b2,
                                                   float* __restrict__ wc,
                                                   int* __restrict__ cursor) {
    __shared__ float part[kFeat][4];
    __shared__ float s2[4];
    int tid  = threadIdx.x;            // == j in [0,256)
    int wave = tid >> 6, lane = tid & 63;
    if (tid < kNB) cursor[tid] = 0;
    float w2 = W2[tid];
    float s = w2;                      // block sum of W2
    #pragma unroll
    for (int o = 32; o > 0; o >>= 1) s += __shfl_down(s, o);
    if (lane == 0) s2[wave] = s;
    for (int t = 0; t < kFeat; ++t) {
        float v = W1[t * kHidden + tid] * w2;   // coalesced within wave
        #pragma unroll
        for (int o = 32; o > 0; o >>= 1) v += __shfl_down(v, o);
        if (lane == 0) part[t][wave] = v;
    }
    __syncthreads();
    if (tid < kFeat)
        wc[tid] = part[tid][0] + part[tid][1] + part[tid][2] + part[tid][3];
    if (tid == 0)
        wc[kFeat] = bias[0] * (s2[0] + s2[1] + s2[2] + s2[3]) + b2[0];
}

// Fat kernel: blocks [0,kBBlk) bucket edges; blocks [kBBlk, kBBlk+kZBlk) compute z.
// Packed entry: (localcol << 17) | row  (row < 2^17, localcol < 2^9).
__global__ __launch_bounds__(256) void fat_kernel(const int* __restrict__ row,
                                                  const int* __restrict__ col,
                                                  const float* __restrict__ x,
                                                  const float* __restrict__ wc,
                                                  int* __restrict__ cursor,
                                                  int* __restrict__ bpacked,
                                                  float* __restrict__ z) {
    if (blockIdx.x < kBBlk) {
        __shared__ int hist[kNB];
        int tid = threadIdx.x;
        for (int t = tid; t < kNB; t += 256) hist[t] = 0;
        __syncthreads();

        int qbase = blockIdx.x * (kEPB / 4);
        const int4* colq = reinterpret_cast<const int4*>(col);
        const int4* rowq = reinterpret_cast<const int4*>(row);
        int4 c4[8];
        #pragma unroll
        for (int k = 0; k < 8; ++k) {
            int q = qbase + k * 256 + tid;
            if (q < kQuads) {
                int4 c = colq[q];
                c4[k] = c;
                atomicAdd(&hist[c.x >> kBShift], 1);   // ds_add, no return
                atomicAdd(&hist[c.y >> kBShift], 1);
                atomicAdd(&hist[c.z >> kBShift], 1);
                atomicAdd(&hist[c.w >> kBShift], 1);
            } else {
                c4[k] = make_int4(-1, -1, -1, -1);
            }
        }
        __syncthreads();
        // One global atomic per (block,bucket). STAGGERED by blockIdx so
        // concurrent blocks hit different cursor addresses (convoy fix).
        int rot = blockIdx.x % kNB;
        for (int t0 = tid; t0 < kNB; t0 += 256) {
            int t = t0 + rot; if (t >= kNB) t -= kNB;
            int c = hist[t];
            hist[t] = c ? atomicAdd(&cursor[t], c) : 0;  // hist -> local cursor
        }
        __syncthreads();
        #pragma unroll
        for (int k = 0; k < 8; ++k) {
            int q = qbase + k * 256 + tid;
            if (q < kQuads) {
                int4 r = rowq[q];
                int cs[4] = {c4[k].x, c4[k].y, c4[k].z, c4[k].w};
                int rs[4] = {r.x, r.y, r.z, r.w};
                #pragma unroll
                for (int u = 0; u < 4; ++u) {
                    int c = cs[u], b = c >> kBShift;
                    int slot = atomicAdd(&hist[b], 1);
                    if (slot < kCap)
                        bpacked[b * kCap + slot] = ((c & (kBSize - 1)) << 17) | rs[u];
                }
            }
        }
    } else {
        // z = x . w
        __shared__ float sw[kFeat];
        if (threadIdx.x < kFeat) sw[threadIdx.x] = wc[threadIdx.x];
        __syncthreads();
        int i = (blockIdx.x - kBBlk) * 256 + threadIdx.x;
        if (i < kNodes) {
            const float4* xp = reinterpret_cast<const float4*>(x + (size_t)i * kFeat);
            float acc = 0.f;
            #pragma unroll
            for (int k = 0; k < kFeat / 4; ++k) {
                float4 v = xp[k];
                acc += v.x * sw[4 * k + 0] + v.y * sw[4 * k + 1]
                     + v.z * sw[4 * k + 2] + v.w * sw[4 * k + 3];
            }
            z[i] = acc;
        }
    }
}

// Degree from bucket entries (LDS only) + per-node finalize: dinv, dy = dinv*z.
__global__ __launch_bounds__(1024) void degfin_kernel(const int* __restrict__ cursor,
                                                      const int* __restrict__ bpacked,
                                                      const float* __restrict__ z,
                                                      float* __restrict__ dinv,
                                                      float* __restrict__ dy) {
    __shared__ int sdeg[kBSize];
    int b = blockIdx.x, tid = threadIdx.x;
    if (tid < kBSize) sdeg[tid] = 0;
    __syncthreads();
    int n = min(cursor[b], kCap);
    int base = b * kCap;
    const int4* bq = reinterpret_cast<const int4*>(bpacked + base);
    int nq = n >> 2;
    for (int i = tid; i < nq; i += 1024) {
        int4 p = bq[i];
        atomicAdd(&sdeg[p.x >> 17], 1);
        atomicAdd(&sdeg[p.y >> 17], 1);
        atomicAdd(&sdeg[p.z >> 17], 1);
        atomicAdd(&sdeg[p.w >> 17], 1);
    }
    if (tid < (n & 3)) atomicAdd(&sdeg[bpacked[base + (n & ~3) + tid] >> 17], 1);
    __syncthreads();
    int node = b * kBSize + tid;
    if (tid < kBSize && node < kNodes) {
        float d  = (float)(sdeg[tid] + 1);   // +1 self-loop; max(d,1) is a no-op
        float di = rsqrtf(d);
        dinv[node] = di;
        dy[node]   = di * z[node];
    }
}

// Aggregate dy over in-edges (LDS atomics) + final combine:
// out = dinv*(ssum + dy) + c    (dinv*dy == dinv^2*z == self-loop term)
__global__ __launch_bounds__(1024) void agg_kernel(const int* __restrict__ cursor,
                                                   const int* __restrict__ bpacked,
                                                   const float* __restrict__ dy,
                                                   const float* __restrict__ dinv,
                                                   const float* __restrict__ wc,
                                                   float* __restrict__ out) {
    __shared__ float ssum[kBSize];
    int b = blockIdx.x, tid = threadIdx.x;
    if (tid < kBSize) ssum[tid] = 0.f;
    __syncthreads();
    int n = min(cursor[b], kCap);
    int base = b * kCap;
    const int4* bq = reinterpret_cast<const int4*>(bpacked + base);
    int nq = n >> 2;
    for (int i = tid; i < nq; i += 1024) {
        int4 p = bq[i];
        atomicAdd(&ssum[p.x >> 17], dy[p.x & 0x1FFFF]);  // L2-resident gathers
        atomicAdd(&ssum[p.y >> 17], dy[p.y & 0x1FFFF]);
        atomicAdd(&ssum[p.z >> 17], dy[p.z & 0x1FFFF]);
        atomicAdd(&ssum[p.w >> 17], dy[p.w & 0x1FFFF]);
    }
    if (tid < (n & 3)) {
        int p = bpacked[base + (n & ~3) + tid];
        atomicAdd(&ssum[p >> 17], dy[p & 0x1FFFF]);
    }
    __syncthreads();
    int node = b * kBSize + tid;
    if (tid < kBSize && node < kNodes)
        out[node] = dinv[node] * (ssum[tid] + dy[node]) + wc[kFeat];
}

extern "C" void kernel_launch(void* const* d_in, const int* in_sizes, int n_in,
                              void* d_out, int out_size, void* d_ws, size_t ws_size,
                              hipStream_t stream) {
    const float* x    = (const float*)d_in[0];
    const int*   ei   = (const int*)d_in[1];   // [2, E]: rows then cols
    const float* W1   = (const float*)d_in[2];
    const float* bias = (const float*)d_in[3];
    const float* W2   = (const float*)d_in[4];
    const float* b2   = (const float*)d_in[5];
    float*       out  = (float*)d_out;

    const int* row = ei;
    const int* col = ei + kEdges;

    // ws layout
    char*  p       = (char*)d_ws;
    float* wc      = (float*)p;                 p += 256;
    int*   cursor  = (int*)p;                   p += 1024;           // kNB ints
    float* z       = (float*)p;                 p += (size_t)kNodes * 4;
    float* dinv    = (float*)p;                 p += (size_t)kNodes * 4;
    float* dy      = (float*)p;                 p += (size_t)kNodes * 4;
    int*   bpacked = (int*)p;                   // kNB * kCap ints (~8 MB)

    prep_kernel<<<1, 256, 0, stream>>>(W1, bias, W2, b2, wc, cursor);
    fat_kernel<<<kBBlk + kZBlk, 256, 0, stream>>>(row, col, x, wc, cursor, bpacked, z);
    degfin_kernel<<<kNB, 1024, 0, stream>>>(cursor, bpacked, z, dinv, dy);
    agg_kernel<<<kNB, 1024, 0, stream>>>(cursor, bpacked, dy, dinv, wc, out);
}

// Round 5
// 111.879 us; speedup vs baseline: 1.1750x; 1.1750x over previous
//
#include <hip/hip_runtime.h>

// GCN classifier, algebraically folded:
//   out = P (x @ (W1 @ W2)) + (bias[0]*sum(W2) + b2[0]),  P = D^-1/2 (A+I) D^-1/2
// NUM_CLASSES==1 collapses the MLP to one 48-vector dot per node (z = x.w);
// linearity lets us propagate scalars. Edge aggregation uses destination
// bucketing (512 ids/bucket) so degree & weighted-sum are LDS atomics, not
// global atomics (R1: 3.2M global atomics cost ~180us).
// R5: revert R4's stagger+shuffle-prep (regressed 16us). Eliminate the serial
// prep stage entirely: z-blocks compute w redundantly (L2/L3-hot W1 reads,
// overlapped with bucket blocks), agg blocks compute the constant c with one
// wave. Only preamble left is a 784B memset of cursor.

constexpr int kNodes  = 100000;
constexpr int kEdges  = 1600000;
constexpr int kFeat   = 48;
constexpr int kHidden = 256;

constexpr int kBShift = 9;                               // 512 node ids / bucket
constexpr int kBSize  = 1 << kBShift;
constexpr int kNB     = (kNodes + kBSize - 1) / kBSize;  // 196 buckets
constexpr int kCap    = 10240;   // slots/bucket; mean 8192, sigma~90 -> +22 sd
constexpr int kEPB    = 8192;    // edges per bucketing block (32/thread)
constexpr int kQuads  = kEdges / 4;                      // 400000 (exact)
constexpr int kBBlk   = (kEdges + kEPB - 1) / kEPB;      // 196 bucket blocks
constexpr int kZBlk   = (kNodes + 255) / 256;            // 391 z blocks

// Fat kernel: blocks [0,kBBlk) bucket edges; blocks [kBBlk, kBBlk+kZBlk)
// compute w = W1@W2 (per-block, cache-hot) then z = x.w.
// Packed entry: (localcol << 17) | row  (row < 2^17, localcol < 2^9).
__global__ __launch_bounds__(256) void fat_kernel(const int* __restrict__ row,
                                                  const int* __restrict__ col,
                                                  const float* __restrict__ x,
                                                  const float* __restrict__ W1,
                                                  const float* __restrict__ W2,
                                                  int* __restrict__ cursor,
                                                  int* __restrict__ bpacked,
                                                  float* __restrict__ z) {
    if (blockIdx.x < kBBlk) {
        __shared__ int hist[kNB];
        int tid = threadIdx.x;
        for (int t = tid; t < kNB; t += 256) hist[t] = 0;
        __syncthreads();

        int qbase = blockIdx.x * (kEPB / 4);
        const int4* colq = reinterpret_cast<const int4*>(col);
        const int4* rowq = reinterpret_cast<const int4*>(row);
        int4 c4[8];
        #pragma unroll
        for (int k = 0; k < 8; ++k) {
            int q = qbase + k * 256 + tid;
            if (q < kQuads) {
                int4 c = colq[q];
                c4[k] = c;
                atomicAdd(&hist[c.x >> kBShift], 1);   // ds_add, no return
                atomicAdd(&hist[c.y >> kBShift], 1);
                atomicAdd(&hist[c.z >> kBShift], 1);
                atomicAdd(&hist[c.w >> kBShift], 1);
            } else {
                c4[k] = make_int4(-1, -1, -1, -1);
            }
        }
        __syncthreads();
        // one global atomic per (block,bucket): reserve a contiguous run
        for (int t = tid; t < kNB; t += 256) {
            int c = hist[t];
            hist[t] = c ? atomicAdd(&cursor[t], c) : 0;  // hist -> local cursor
        }
        __syncthreads();
        #pragma unroll
        for (int k = 0; k < 8; ++k) {
            int q = qbase + k * 256 + tid;
            if (q < kQuads) {
                int4 r = rowq[q];
                int cs[4] = {c4[k].x, c4[k].y, c4[k].z, c4[k].w};
                int rs[4] = {r.x, r.y, r.z, r.w};
                #pragma unroll
                for (int u = 0; u < 4; ++u) {
                    int c = cs[u], b = c >> kBShift;
                    int slot = atomicAdd(&hist[b], 1);
                    if (slot < kCap)
                        bpacked[b * kCap + slot] = ((c & (kBSize - 1)) << 17) | rs[u];
                }
            }
        }
    } else {
        // w = W1 @ W2 (redundant per block; W1/W2 are L2/L3-hot), then z = x.w
        __shared__ float sw2[kHidden];           // 1 KB
        __shared__ float spart[kFeat * 4];
        __shared__ float sw[kFeat];
        int tid = threadIdx.x;
        sw2[tid] = W2[tid];
        __syncthreads();
        if (tid < kFeat * 4) {                   // 192 threads, 64 MACs each
            int t = tid >> 2, q = tid & 3;
            const float4* wr = reinterpret_cast<const float4*>(W1 + t * kHidden + q * 64);
            const float4* b4 = reinterpret_cast<const float4*>(sw2) + q * 16;
            float a = 0.f;
            #pragma unroll
            for (int j = 0; j < 16; ++j) {
                float4 u = wr[j];
                float4 v = b4[j];
                a += u.x * v.x + u.y * v.y + u.z * v.z + u.w * v.w;
            }
            spart[tid] = a;
        }
        __syncthreads();
        if (tid < kFeat)
            sw[tid] = spart[4 * tid] + spart[4 * tid + 1]
                    + spart[4 * tid + 2] + spart[4 * tid + 3];
        __syncthreads();
        int i = (blockIdx.x - kBBlk) * 256 + tid;
        if (i < kNodes) {
            const float4* xp = reinterpret_cast<const float4*>(x + (size_t)i * kFeat);
            float acc = 0.f;
            #pragma unroll
            for (int k = 0; k < kFeat / 4; ++k) {
                float4 v = xp[k];
                acc += v.x * sw[4 * k + 0] + v.y * sw[4 * k + 1]
                     + v.z * sw[4 * k + 2] + v.w * sw[4 * k + 3];
            }
            z[i] = acc;
        }
    }
}

// Degree from bucket entries (LDS only) + per-node finalize: dinv, dy = dinv*z.
__global__ __launch_bounds__(1024) void degfin_kernel(const int* __restrict__ cursor,
                                                      const int* __restrict__ bpacked,
                                                      const float* __restrict__ z,
                                                      float* __restrict__ dinv,
                                                      float* __restrict__ dy) {
    __shared__ int sdeg[kBSize];
    int b = blockIdx.x, tid = threadIdx.x;
    if (tid < kBSize) sdeg[tid] = 0;
    __syncthreads();
    int n = min(cursor[b], kCap);
    int base = b * kCap;
    const int4* bq = reinterpret_cast<const int4*>(bpacked + base);
    int nq = n >> 2;
    for (int i = tid; i < nq; i += 1024) {
        int4 p = bq[i];
        atomicAdd(&sdeg[p.x >> 17], 1);
        atomicAdd(&sdeg[p.y >> 17], 1);
        atomicAdd(&sdeg[p.z >> 17], 1);
        atomicAdd(&sdeg[p.w >> 17], 1);
    }
    if (tid < (n & 3)) atomicAdd(&sdeg[bpacked[base + (n & ~3) + tid] >> 17], 1);
    __syncthreads();
    int node = b * kBSize + tid;
    if (tid < kBSize && node < kNodes) {
        float d  = (float)(sdeg[tid] + 1);   // +1 self-loop; max(d,1) is a no-op
        float di = rsqrtf(d);
        dinv[node] = di;
        dy[node]   = di * z[node];
    }
}

// Aggregate dy over in-edges (LDS atomics) + final combine:
// out = dinv*(ssum + dy) + c    (dinv*dy == dinv^2*z == self-loop term)
// c = bias[0]*sum(W2) + b2[0], computed by wave 0 (cache-hot reads).
__global__ __launch_bounds__(1024) void agg_kernel(const int* __restrict__ cursor,
                                                   const int* __restrict__ bpacked,
                                                   const float* __restrict__ dy,
                                                   const float* __restrict__ dinv,
                                                   const float* __restrict__ bias,
                                                   const float* __restrict__ W2,
                                                   const float* __restrict__ b2,
                                                   float* __restrict__ out) {
    __shared__ float ssum[kBSize];
    __shared__ float sc;
    int b = blockIdx.x, tid = threadIdx.x;
    if (tid < kBSize) ssum[tid] = 0.f;
    if (tid < 64) {                              // one wave computes c
        const float4* w2q = reinterpret_cast<const float4*>(W2);
        float4 v = w2q[tid];
        float s = v.x + v.y + v.z + v.w;
        #pragma unroll
        for (int o = 32; o > 0; o >>= 1) s += __shfl_down(s, o);
        if (tid == 0) sc = bias[0] * s + b2[0];
    }
    __syncthreads();
    int n = min(cursor[b], kCap);
    int base = b * kCap;
    const int4* bq = reinterpret_cast<const int4*>(bpacked + base);
    int nq = n >> 2;
    for (int i = tid; i < nq; i += 1024) {
        int4 p = bq[i];
        atomicAdd(&ssum[p.x >> 17], dy[p.x & 0x1FFFF]);  // L2/L3-resident gathers
        atomicAdd(&ssum[p.y >> 17], dy[p.y & 0x1FFFF]);
        atomicAdd(&ssum[p.z >> 17], dy[p.z & 0x1FFFF]);
        atomicAdd(&ssum[p.w >> 17], dy[p.w & 0x1FFFF]);
    }
    if (tid < (n & 3)) {
        int p = bpacked[base + (n & ~3) + tid];
        atomicAdd(&ssum[p >> 17], dy[p & 0x1FFFF]);
    }
    __syncthreads();
    int node = b * kBSize + tid;
    if (tid < kBSize && node < kNodes)
        out[node] = dinv[node] * (ssum[tid] + dy[node]) + sc;
}

extern "C" void kernel_launch(void* const* d_in, const int* in_sizes, int n_in,
                              void* d_out, int out_size, void* d_ws, size_t ws_size,
                              hipStream_t stream) {
    const float* x    = (const float*)d_in[0];
    const int*   ei   = (const int*)d_in[1];   // [2, E]: rows then cols
    const float* W1   = (const float*)d_in[2];
    const float* bias = (const float*)d_in[3];
    const float* W2   = (const float*)d_in[4];
    const float* b2   = (const float*)d_in[5];
    float*       out  = (float*)d_out;

    const int* row = ei;
    const int* col = ei + kEdges;

    // ws layout
    char*  p       = (char*)d_ws;
    int*   cursor  = (int*)p;                   p += 1024;           // kNB ints
    float* z       = (float*)p;                 p += (size_t)kNodes * 4;
    float* dinv    = (float*)p;                 p += (size_t)kNodes * 4;
    float* dy      = (float*)p;                 p += (size_t)kNodes * 4;
    int*   bpacked = (int*)p;                   // kNB * kCap ints (~8 MB)

    hipMemsetAsync(cursor, 0, kNB * sizeof(int), stream);
    fat_kernel<<<kBBlk + kZBlk, 256, 0, stream>>>(row, col, x, W1, W2, cursor, bpacked, z);
    degfin_kernel<<<kNB, 1024, 0, stream>>>(cursor, bpacked, z, dinv, dy);
    agg_kernel<<<kNB, 1024, 0, stream>>>(cursor, bpacked, dy, dinv, bias, W2, b2, out);
}

// Round 7
// 108.440 us; speedup vs baseline: 1.2122x; 1.0317x over previous
//
#include <hip/hip_runtime.h>

// GCN classifier, algebraically folded:
//   out = P (x @ (W1 @ W2)) + (bias[0]*sum(W2) + b2[0]),  P = D^-1/2 (A+I) D^-1/2
// NUM_CLASSES==1 collapses the MLP to one 48-vector dot per node (z = x.w);
// linearity lets us propagate scalars. Edge aggregation uses destination
// bucketing (512 ids/bucket) so degree & weighted-sum are LDS atomics.
// R7: revert R6's cooperative-launch fusion (launch was rejected -> out never
// written). Keep its LDS counting-sort: bucket phase stages 8192 entries in
// LDS via prefix-scanned histogram, then writes per-bucket runs to bpacked
// COALESCED (R5 scattered ~1.6M 4B stores ~= 51MB effective write traffic).

constexpr int kNodes  = 100000;
constexpr int kEdges  = 1600000;
constexpr int kFeat   = 48;
constexpr int kHidden = 256;

constexpr int kBShift = 9;                 // 512 node ids / bucket
constexpr int kBSize  = 1 << kBShift;
constexpr int kNB     = 196;               // buckets
constexpr int kEPB    = 8192;              // edges per bucket block
constexpr int kQuads  = kEdges / 4;        // 400000 (exact)
constexpr int kBBlk   = (kEdges + kEPB - 1) / kEPB;  // 196 bucket blocks
constexpr int kZBlk   = (kNodes + 511) / 512;        // 196 z blocks
constexpr int kCap    = 10240;             // slots/bucket; mean 8163, +23 sigma

// Fat kernel (512 thr): blocks [0,kBBlk) bucket edges via LDS counting sort;
// blocks [kBBlk, kBBlk+kZBlk) compute w = W1@W2 (cache-hot) then z = x.w.
// Packed entry: (localcol << 17) | row  (row < 2^17, localcol < 2^9).
__global__ __launch_bounds__(512) void fat_kernel(const int* __restrict__ row,
                                                  const int* __restrict__ col,
                                                  const float* __restrict__ x,
                                                  const float* __restrict__ W1,
                                                  const float* __restrict__ W2,
                                                  int* __restrict__ cursor,
                                                  int* __restrict__ bpacked,
                                                  float* __restrict__ z) {
    __shared__ int stage[kEPB];        // 32 KB staging for counting sort
    __shared__ int hist[256];
    __shared__ int lstart[256];
    __shared__ int lcur[256];
    __shared__ int gbase[256];
    __shared__ int scan[256];
    const int tid = threadIdx.x;

    if (blockIdx.x < kBBlk) {
        if (tid < 256) hist[tid] = 0;
        __syncthreads();

        int qbase = blockIdx.x * (kEPB / 4);
        const int4* colq = reinterpret_cast<const int4*>(col);
        const int4* rowq = reinterpret_cast<const int4*>(row);
        int4 c4[4];
        #pragma unroll
        for (int k = 0; k < 4; ++k) {
            int q = qbase + k * 512 + tid;
            if (q < kQuads) {
                c4[k] = colq[q];
                atomicAdd(&hist[c4[k].x >> kBShift], 1);   // ds_add, no return
                atomicAdd(&hist[c4[k].y >> kBShift], 1);
                atomicAdd(&hist[c4[k].z >> kBShift], 1);
                atomicAdd(&hist[c4[k].w >> kBShift], 1);
            } else {
                c4[k] = make_int4(-1, -1, -1, -1);
            }
        }
        __syncthreads();
        // exclusive scan of hist -> lstart (Hillis-Steele over 256 lanes)
        int h = 0;
        if (tid < 256) { h = hist[tid]; scan[tid] = h; }
        __syncthreads();
        for (int off = 1; off < 256; off <<= 1) {
            int v = 0;
            if (tid < 256 && tid >= off) v = scan[tid - off];
            __syncthreads();
            if (tid < 256) scan[tid] += v;
            __syncthreads();
        }
        if (tid < 256) {
            int ls = scan[tid] - h;            // exclusive prefix
            lstart[tid] = ls;
            lcur[tid]   = ls;
            gbase[tid]  = (tid < kNB && h > 0) ? atomicAdd(&cursor[tid], h) : 0;
        }
        __syncthreads();
        // counting-sort scatter into LDS (cheap, banked)
        #pragma unroll
        for (int k = 0; k < 4; ++k) {
            int q = qbase + k * 512 + tid;
            if (q < kQuads) {
                int4 r = rowq[q];
                int cs[4] = {c4[k].x, c4[k].y, c4[k].z, c4[k].w};
                int rs[4] = {r.x, r.y, r.z, r.w};
                #pragma unroll
                for (int u = 0; u < 4; ++u) {
                    int c = cs[u], b = c >> kBShift;
                    int s = atomicAdd(&lcur[b], 1);        // ds_add_rtn
                    stage[s] = ((c & (kBSize - 1)) << 17) | rs[u];
                }
            }
        }
        __syncthreads();
        // coalesced copy of per-bucket runs: wave w handles buckets w, w+8, ...
        int wave = tid >> 6, lane = tid & 63;
        for (int b = wave; b < kNB; b += 8) {
            int n  = hist[b];
            int ls = lstart[b];
            int gb = gbase[b];
            for (int i = lane; i < n; i += 64) {
                int g = gb + i;
                if (g < kCap) bpacked[b * kCap + g] = stage[ls + i];
            }
        }
    } else {
        // w = W1 @ W2 (redundant per block; W1/W2 cache-hot), then z = x.w
        float* sw2   = reinterpret_cast<float*>(stage);           // 256 floats
        float* spart = reinterpret_cast<float*>(stage) + 256;     // 192 floats
        float* swv   = reinterpret_cast<float*>(stage) + 512;     // 48 floats
        if (tid < kHidden) sw2[tid] = W2[tid];
        __syncthreads();
        if (tid < kFeat * 4) {                  // 192 threads, 64 MACs each
            int t = tid >> 2, q = tid & 3;
            const float4* wr = reinterpret_cast<const float4*>(W1 + t * kHidden + q * 64);
            const float4* b4 = reinterpret_cast<const float4*>(sw2) + q * 16;
            float a = 0.f;
            #pragma unroll
            for (int j = 0; j < 16; ++j) {
                float4 u = wr[j];
                float4 v = b4[j];
                a += u.x * v.x + u.y * v.y + u.z * v.z + u.w * v.w;
            }
            spart[tid] = a;
        }
        __syncthreads();
        if (tid < kFeat)
            swv[tid] = spart[4 * tid] + spart[4 * tid + 1]
                     + spart[4 * tid + 2] + spart[4 * tid + 3];
        __syncthreads();
        int i = (blockIdx.x - kBBlk) * 512 + tid;
        if (i < kNodes) {
            const float4* xp = reinterpret_cast<const float4*>(x + (size_t)i * kFeat);
            float acc = 0.f;
            #pragma unroll
            for (int k = 0; k < kFeat / 4; ++k) {
                float4 v = xp[k];
                acc += v.x * swv[4 * k + 0] + v.y * swv[4 * k + 1]
                     + v.z * swv[4 * k + 2] + v.w * swv[4 * k + 3];
            }
            z[i] = acc;
        }
    }
}

// Degree from bucket entries (LDS only) + per-node finalize: dinv, dy = dinv*z.
__global__ __launch_bounds__(1024) void degfin_kernel(const int* __restrict__ cursor,
                                                      const int* __restrict__ bpacked,
                                                      const float* __restrict__ z,
                                                      float* __restrict__ dinv,
                                                      float* __restrict__ dy) {
    __shared__ int sdeg[kBSize];
    int b = blockIdx.x, tid = threadIdx.x;
    if (tid < kBSize) sdeg[tid] = 0;
    __syncthreads();
    int n = min(cursor[b], kCap);
    int base = b * kCap;
    const int4* bq = reinterpret_cast<const int4*>(bpacked + base);
    int nq = n >> 2;
    for (int i = tid; i < nq; i += 1024) {
        int4 p = bq[i];
        atomicAdd(&sdeg[p.x >> 17], 1);
        atomicAdd(&sdeg[p.y >> 17], 1);
        atomicAdd(&sdeg[p.z >> 17], 1);
        atomicAdd(&sdeg[p.w >> 17], 1);
    }
    if (tid < (n & 3)) atomicAdd(&sdeg[bpacked[base + (n & ~3) + tid] >> 17], 1);
    __syncthreads();
    int node = b * kBSize + tid;
    if (tid < kBSize && node < kNodes) {
        float d  = (float)(sdeg[tid] + 1);   // +1 self-loop; max(d,1) is a no-op
        float di = rsqrtf(d);
        dinv[node] = di;
        dy[node]   = di * z[node];
    }
}

// Aggregate dy over in-edges (LDS atomics) + final combine:
// out = dinv*(ssum + dy) + c    (dinv*dy == dinv^2*z == self-loop term)
// c = bias[0]*sum(W2) + b2[0], computed by wave 0 (cache-hot reads).
__global__ __launch_bounds__(1024) void agg_kernel(const int* __restrict__ cursor,
                                                   const int* __restrict__ bpacked,
                                                   const float* __restrict__ dy,
                                                   const float* __restrict__ dinv,
                                                   const float* __restrict__ bias,
                                                   const float* __restrict__ W2,
                                                   const float* __restrict__ b2,
                                                   float* __restrict__ out) {
    __shared__ float ssum[kBSize];
    __shared__ float sc;
    int b = blockIdx.x, tid = threadIdx.x;
    if (tid < kBSize) ssum[tid] = 0.f;
    if (tid < 64) {                              // one wave computes c
        const float4* w2q = reinterpret_cast<const float4*>(W2);
        float4 v = w2q[tid];
        float s = v.x + v.y + v.z + v.w;
        #pragma unroll
        for (int o = 32; o > 0; o >>= 1) s += __shfl_down(s, o);
        if (tid == 0) sc = bias[0] * s + b2[0];
    }
    __syncthreads();
    int n = min(cursor[b], kCap);
    int base = b * kCap;
    const int4* bq = reinterpret_cast<const int4*>(bpacked + base);
    int nq = n >> 2;
    for (int i = tid; i < nq; i += 1024) {
        int4 p = bq[i];
        atomicAdd(&ssum[p.x >> 17], dy[p.x & 0x1FFFF]);  // L2/L3-resident gathers
        atomicAdd(&ssum[p.y >> 17], dy[p.y & 0x1FFFF]);
        atomicAdd(&ssum[p.z >> 17], dy[p.z & 0x1FFFF]);
        atomicAdd(&ssum[p.w >> 17], dy[p.w & 0x1FFFF]);
    }
    if (tid < (n & 3)) {
        int p = bpacked[base + (n & ~3) + tid];
        atomicAdd(&ssum[p >> 17], dy[p & 0x1FFFF]);
    }
    __syncthreads();
    int node = b * kBSize + tid;
    if (tid < kBSize && node < kNodes)
        out[node] = dinv[node] * (ssum[tid] + dy[node]) + sc;
}

extern "C" void kernel_launch(void* const* d_in, const int* in_sizes, int n_in,
                              void* d_out, int out_size, void* d_ws, size_t ws_size,
                              hipStream_t stream) {
    const float* x    = (const float*)d_in[0];
    const int*   ei   = (const int*)d_in[1];   // [2, E]: rows then cols
    const float* W1   = (const float*)d_in[2];
    const float* bias = (const float*)d_in[3];
    const float* W2   = (const float*)d_in[4];
    const float* b2   = (const float*)d_in[5];
    float*       out  = (float*)d_out;

    const int* row = ei;
    const int* col = ei + kEdges;

    // ws layout
    char*  p       = (char*)d_ws;
    int*   cursor  = (int*)p;                   p += 1024;           // kNB ints
    float* z       = (float*)p;                 p += (size_t)kNodes * 4;
    float* dinv    = (float*)p;                 p += (size_t)kNodes * 4;
    float* dy      = (float*)p;                 p += (size_t)kNodes * 4;
    int*   bpacked = (int*)p;                   // kNB * kCap ints (~8 MB)

    hipMemsetAsync(cursor, 0, kNB * sizeof(int), stream);
    fat_kernel<<<kBBlk + kZBlk, 512, 0, stream>>>(row, col, x, W1, W2, cursor, bpacked, z);
    degfin_kernel<<<kNB, 1024, 0, stream>>>(cursor, bpacked, z, dinv, dy);
    agg_kernel<<<kNB, 1024, 0, stream>>>(cursor, bpacked, dy, dinv, bias, W2, b2, out);
}